// Round 3
// baseline (1254.105 us; speedup 1.0000x reference)
//
#include <hip/hip_runtime.h>
#include <hip/hip_bf16.h>
#include <stdint.h>

#define B_ 4
#define N_ 8192
#define D_ 128
#define E_ 262144

typedef __bf16 bf16x8 __attribute__((ext_vector_type(8)));
typedef unsigned short u16x8 __attribute__((ext_vector_type(8)));
typedef float f32x4 __attribute__((ext_vector_type(4)));

constexpr int HASH_LOG = 20;
constexpr unsigned HASH_SIZE = 1u << HASH_LOG;
constexpr unsigned HASH_MASK = HASH_SIZE - 1u;

// ws layout (bytes):
constexpr size_t OFF_HB   = 0;          // bf16 h  [B][N][D]   8,388,608 B
constexpr size_t OFF_W1T  = 8388608;    // bf16 W1^T [128][256]   65,536 B
constexpr size_t OFF_HASH = 8454144;    // u64 hash  [1<<20]   8,388,608 B
constexpr size_t OFF_WIN  = 16842752;   // u8 winner [E]         262,144 B

__device__ __forceinline__ unsigned short f2bf(float f) {
  union { float f; unsigned u; } v; v.f = f;
  unsigned r = v.u + 0x7fffu + ((v.u >> 16) & 1u);  // RNE
  return (unsigned short)(r >> 16);
}

__global__ void cast_h_k(const float* __restrict__ h, unsigned short* __restrict__ o) {
  int i = blockIdx.x * blockDim.x + threadIdx.x;   // 1,048,576 threads x 4 elems
  float4 v = reinterpret_cast<const float4*>(h)[i];
  ushort4 r;
  r.x = f2bf(v.x); r.y = f2bf(v.y); r.z = f2bf(v.z); r.w = f2bf(v.w);
  reinterpret_cast<ushort4*>(o)[i] = r;
}

__global__ void tw1_k(const float* __restrict__ W1, unsigned short* __restrict__ o) {
  int i = blockIdx.x * blockDim.x + threadIdx.x;   // 32768: i = d*256 + k
  int d = i >> 8, k = i & 255;
  o[i] = f2bf(W1[k * 128 + d]);
}

__global__ void hash_insert_k(const int* __restrict__ ei,
                              unsigned long long* __restrict__ tab) {
  int e = blockIdx.x * blockDim.x + threadIdx.x;
  unsigned s = (unsigned)ei[e];
  unsigned d = (unsigned)ei[E_ + e];
  unsigned key = s * (unsigned)N_ + d;             // < 2^26
  unsigned long long pack = (((unsigned long long)(key + 1u)) << 32) | (unsigned long long)(unsigned)e;
  unsigned slot = (key * 2654435761u) & HASH_MASK;
  for (;;) {
    unsigned long long cur = tab[slot];
    if (cur == 0ull) {
      unsigned long long prev = atomicCAS(&tab[slot], 0ull, pack);
      if (prev == 0ull) return;
      cur = prev;
    }
    if ((cur >> 32) == (unsigned long long)(key + 1u)) {
      atomicMax(&tab[slot], pack);                 // same key: max edge id wins
      return;
    }
    slot = (slot + 1u) & HASH_MASK;
  }
}

__global__ void winner_k(const int* __restrict__ ei,
                         const unsigned long long* __restrict__ tab,
                         unsigned char* __restrict__ win) {
  int e = blockIdx.x * blockDim.x + threadIdx.x;
  unsigned s = (unsigned)ei[e];
  unsigned d = (unsigned)ei[E_ + e];
  unsigned key = s * (unsigned)N_ + d;
  unsigned slot = (key * 2654435761u) & HASH_MASK;
  for (;;) {
    unsigned long long cur = tab[slot];
    if ((cur >> 32) == (unsigned long long)(key + 1u)) {
      win[e] = ((unsigned)(cur & 0xffffffffull) == (unsigned)e) ? 1 : 0;
      return;
    }
    slot = (slot + 1u) & HASH_MASK;
  }
}

// 64 edges/block: M = 256 rows (row = e_local*4 + b), K = 256, N = 128.
// 4 waves, wave w owns rows [w*64, w*64+64). mfma_f32_16x16x32_bf16.
__global__ __launch_bounds__(256, 2) void edge_mlp_k(
    const int* __restrict__ ei,
    const unsigned short* __restrict__ hb,    // bf16 bits [B][N][D]
    const unsigned short* __restrict__ w1t,   // bf16 bits [128][256]
    const float* __restrict__ b1,
    const float* __restrict__ w2,
    const float* __restrict__ b2,
    const unsigned char* __restrict__ win,
    float* __restrict__ out) {
  __shared__ char lds[65536];                 // W1^T, XOR-swizzled rows of 512 B
  const int tid  = threadIdx.x;
  const int lane = tid & 63;
  const int wid  = tid >> 6;
  const int l15  = lane & 15;
  const int lg   = lane >> 4;

  // stage W1^T -> LDS with byte ^= ((row&7)<<4) swizzle (conflict-free ds_read_b128)
  {
    const uint4* g = reinterpret_cast<const uint4*>(w1t);
    #pragma unroll
    for (int it = 0; it < 16; ++it) {
      int i = it * 256 + tid;                 // uint4 index, 4096 total
      uint4 v = g[i];
      int byte = i * 16;
      int dd = byte >> 9;
      int within = byte & 511;
      *reinterpret_cast<uint4*>(&lds[dd * 512 + (within ^ ((dd & 7) << 4))]) = v;
    }
  }

  const int e0 = blockIdx.x * 64;

  // per-lane row -> gather bases (element offsets into hb)
  unsigned offS[4], offD[4];
  #pragma unroll
  for (int m = 0; m < 4; ++m) {
    int row = wid * 64 + m * 16 + l15;
    int e = e0 + (row >> 2);
    int b = row & 3;
    unsigned sn = (unsigned)ei[e];
    unsigned dn = (unsigned)ei[E_ + e];
    offS[m] = ((unsigned)b * N_ + sn) * D_;
    offD[m] = ((unsigned)b * N_ + dn) * D_;
  }

  __syncthreads();

  f32x4 acc[4][8];
  #pragma unroll
  for (int m = 0; m < 4; ++m)
    #pragma unroll
    for (int n = 0; n < 8; ++n)
      acc[m][n] = (f32x4){0.f, 0.f, 0.f, 0.f};

  const int kg = 8 * lg;  // lane's k-chunk within the 32-wide K-step

  #pragma unroll
  for (int ks = 0; ks < 8; ++ks) {
    bf16x8 a[4];
    const int kin = (ks & 3) * 32 + kg;       // offset within the 128-elem half
    #pragma unroll
    for (int m = 0; m < 4; ++m) {
      unsigned off = (ks < 4 ? offS[m] : offD[m]) + (unsigned)kin;
      u16x8 u = *reinterpret_cast<const u16x8*>(hb + off);
      a[m] = __builtin_bit_cast(bf16x8, u);
    }
    bf16x8 bfr[8];
    const int kb = ks * 64 + 16 * lg;         // byte offset within a W1^T row
    #pragma unroll
    for (int n = 0; n < 8; ++n) {
      int dd = n * 16 + l15;
      uint4 v = *reinterpret_cast<const uint4*>(&lds[dd * 512 + (kb ^ ((dd & 7) << 4))]);
      bfr[n] = __builtin_bit_cast(bf16x8, v);
    }
    #pragma unroll
    for (int n = 0; n < 8; ++n)
      #pragma unroll
      for (int m = 0; m < 4; ++m)
        acc[m][n] = __builtin_amdgcn_mfma_f32_16x16x32_bf16(a[m], bfr[n], acc[m][n], 0, 0, 0);
  }

  // epilogue: bias + SiLU + dot with W2, reduce over the 128 cols
  float b1v[8], w2v[8];
  #pragma unroll
  for (int n = 0; n < 8; ++n) {
    int col = n * 16 + l15;
    b1v[n] = b1[col];
    w2v[n] = w2[col];
  }
  float sc[4][4];
  #pragma unroll
  for (int m = 0; m < 4; ++m)
    #pragma unroll
    for (int i = 0; i < 4; ++i) sc[m][i] = 0.f;
  #pragma unroll
  for (int n = 0; n < 8; ++n)
    #pragma unroll
    for (int m = 0; m < 4; ++m)
      #pragma unroll
      for (int i = 0; i < 4; ++i) {
        float v = acc[m][n][i] + b1v[n];
        float sv = v / (1.f + __expf(-v));    // SiLU
        sc[m][i] += sv * w2v[n];
      }
  // butterfly reduce across the 16 lanes holding one row's cols
  #pragma unroll
  for (int m = 0; m < 4; ++m)
    #pragma unroll
    for (int i = 0; i < 4; ++i) {
      float v = sc[m][i];
      v += __shfl_xor(v, 1, 64);
      v += __shfl_xor(v, 2, 64);
      v += __shfl_xor(v, 4, 64);
      v += __shfl_xor(v, 8, 64);
      sc[m][i] = v;
    }
  const float b2v = b2[0];
  if (l15 == 0) {
    #pragma unroll
    for (int m = 0; m < 4; ++m) {
      int el = wid * 16 + m * 4 + lg;         // row>>2 for rows this lane holds
      int e = e0 + el;
      if (win[e]) {
        unsigned sn = (unsigned)ei[e];
        unsigned dn = (unsigned)ei[E_ + e];
        size_t base = (size_t)sn * N_ + dn;
        #pragma unroll
        for (int i = 0; i < 4; ++i)           // i == batch (row&3)
          out[(size_t)i * ((size_t)N_ * (size_t)N_) + base] = sc[m][i] + b2v;
      }
    }
  }
}

extern "C" void kernel_launch(void* const* d_in, const int* in_sizes, int n_in,
                              void* d_out, int out_size, void* d_ws, size_t ws_size,
                              hipStream_t stream) {
  const float* h  = (const float*)d_in[0];
  const int*   ei = (const int*)d_in[1];     // harness stores integer inputs as int32
  const float* W1 = (const float*)d_in[2];
  const float* b1 = (const float*)d_in[3];
  const float* W2 = (const float*)d_in[4];
  const float* b2 = (const float*)d_in[5];
  float* out = (float*)d_out;
  char*  ws  = (char*)d_ws;

  unsigned short*     hb   = (unsigned short*)(ws + OFF_HB);
  unsigned short*     w1t  = (unsigned short*)(ws + OFF_W1T);
  unsigned long long* tab  = (unsigned long long*)(ws + OFF_HASH);
  unsigned char*      win  = (unsigned char*)(ws + OFF_WIN);

  // 1 GiB zero of the scatter target (out re-poisoned every launch)
  (void)hipMemsetAsync(d_out, 0, (size_t)out_size * sizeof(float), stream);
  (void)hipMemsetAsync(tab, 0, (size_t)HASH_SIZE * 8, stream);

  cast_h_k<<<4096, 256, 0, stream>>>(h, hb);
  tw1_k<<<128, 256, 0, stream>>>(W1, w1t);
  hash_insert_k<<<E_ / 256, 256, 0, stream>>>(ei, tab);
  winner_k<<<E_ / 256, 256, 0, stream>>>(ei, tab, win);
  edge_mlp_k<<<E_ / 64, 256, 0, stream>>>(ei, hb, w1t, b1, W2, b2, win, out);
}